// Round 2
// baseline (45.268 us; speedup 1.0000x reference)
//
#include <hip/hip_runtime.h>
#include <math.h>

// SPSA on f(x) = x0^2 + Q*x1^2, Q=8. Step is affine: x' = S(d,k) x,
//   S = [[1+nw, nw*qs],[nws, 1+nws*qs]],  nw = -2*ak, qs = Q*s, nws = nw*s,
//   s = d0*d1 in {-1,+1}.  ck cancels exactly.
// Parallelize the sequential scan: x_final = (prod_k S_k) x_init.
// 8 segments of n/8 iterations; each thread computes a 2x2 segment product
// (6 FMAs/step); per-block LDS combine folds 8 matrices into x.
// 16384 traj x 8 seg = 131072 threads = 2048 waves = 8 waves/CU.

#define BLK  256
#define TPB  32          // trajectories per block
#define NSEG 8
#define UNR  25          // int2 loads per chunk per lane

__global__ __launch_bounds__(BLK, 2) void spsa_kernel(
    const float2* __restrict__ X0,
    const int2*   __restrict__ bits,   // (n, bs) int2 of {0,1} bits
    const float*  __restrict__ a_arr,
    float2*       __restrict__ out,
    int n, int bs, int A)
{
    __shared__ float s_nw[1024];             // n <= 1024 (n = 1000 here)
    __shared__ float s_m[NSEG][TPB][4];

    const int tid  = threadIdx.x;
    const int traj = tid & (TPB - 1);
    const int seg  = tid >> 5;
    int b          = blockIdx.x * TPB + traj;
    const bool act = (b < bs);
    if (!act) b = bs - 1;                    // clamp for safe (discarded) loads

    const int seglen = (n + NSEG - 1) / NSEG;        // 125 for n=1000
    const int k0  = seg * seglen;
    const int cnt = max(0, min(n, k0 + seglen) - k0);
    const int nch = cnt / UNR;                        // 5 for n=1000

    const int2* p = bits + (size_t)k0 * bs + b;

    int2 bufA[UNR], bufB[UNR];

    // Issue prologue loads FIRST so HBM latency hides under table setup.
    if (nch > 0) {
        #pragma unroll
        for (int j = 0; j < UNR; ++j) bufA[j] = p[(size_t)j * bs];
    }

    // Coefficient table: nw[k] = -2 * a[k] / (k+2+A)^0.602
    for (int k = tid; k < n; k += BLK) {
        float base = (float)(k + 2 + A);
        s_nw[k] = -2.0f * a_arr[k] / powf(base, 0.602f);
    }
    __syncthreads();

    // Segment product M = S_{k1-1} * ... * S_{k0}, accumulated in registers.
    float m00 = 1.f, m01 = 0.f, m10 = 0.f, m11 = 1.f;

    auto step = [&](int2 d, float nw) {
        unsigned sb = ((unsigned)(d.x ^ d.y)) << 31;        // sign of s
        float qs  = __uint_as_float(0x41000000u ^ sb);      // +-8.0
        float nws = __uint_as_float(__float_as_uint(nw) ^ sb);
        float u0 = fmaf(qs, m10, m00);
        float u1 = fmaf(qs, m11, m01);
        m00 = fmaf(nw,  u0, m00);
        m01 = fmaf(nw,  u1, m01);
        m10 = fmaf(nws, u0, m10);
        m11 = fmaf(nws, u1, m11);
    };

    // Software-pipelined, double-buffered (static reg indexing only).
    for (int ch = 0; ch < nch; ch += 2) {
        if (ch + 1 < nch) {
            const int2* q = p + (size_t)(ch + 1) * UNR * bs;
            #pragma unroll
            for (int j = 0; j < UNR; ++j) bufB[j] = q[(size_t)j * bs];
        }
        {
            const int kb = k0 + ch * UNR;
            #pragma unroll
            for (int j = 0; j < UNR; ++j) step(bufA[j], s_nw[kb + j]);
        }
        if (ch + 2 < nch) {
            const int2* q = p + (size_t)(ch + 2) * UNR * bs;
            #pragma unroll
            for (int j = 0; j < UNR; ++j) bufA[j] = q[(size_t)j * bs];
        }
        if (ch + 1 < nch) {
            const int kb = k0 + (ch + 1) * UNR;
            #pragma unroll
            for (int j = 0; j < UNR; ++j) step(bufB[j], s_nw[kb + j]);
        }
    }
    for (int k = nch * UNR; k < cnt; ++k) step(p[(size_t)k * bs], s_nw[k0 + k]);

    s_m[seg][traj][0] = m00; s_m[seg][traj][1] = m01;
    s_m[seg][traj][2] = m10; s_m[seg][traj][3] = m11;
    __syncthreads();

    // Combine: first 32 threads fold the 8 segment matrices into x.
    if (seg == 0 && act) {
        float2 xin = X0[b];
        float v0 = xin.x * 20.0f - 10.0f;
        float v1 = xin.y * 20.0f - 10.0f;
        #pragma unroll
        for (int s = 0; s < NSEG; ++s) {
            float a00 = s_m[s][traj][0], a01 = s_m[s][traj][1];
            float a10 = s_m[s][traj][2], a11 = s_m[s][traj][3];
            float t0 = fmaf(a00, v0, a01 * v1);
            float t1 = fmaf(a10, v0, a11 * v1);
            v0 = t0; v1 = t1;
        }
        out[b] = make_float2(v0, v1);
    }
}

extern "C" void kernel_launch(void* const* d_in, const int* in_sizes, int n_in,
                              void* d_out, int out_size, void* d_ws, size_t ws_size,
                              hipStream_t stream) {
    const float2* X0   = (const float2*)d_in[0];
    const float*  a    = (const float*) d_in[1];
    // d_in[2] = c (cancels exactly, unused)
    const int2*   bits = (const int2*)  d_in[3];
    float2*       out  = (float2*)d_out;

    const int bs = in_sizes[0] / 2;
    const int n  = in_sizes[1];
    const int A  = (int)floor(0.1 * (double)n);

    const int grid = (bs + TPB - 1) / TPB;
    spsa_kernel<<<grid, BLK, 0, stream>>>(X0, bits, a, out, n, bs, A);
}

// Round 3
// 32.342 us; speedup vs baseline: 1.3997x; 1.3997x over previous
//
#include <hip/hip_runtime.h>
#include <math.h>

// SPSA on f(x) = x0^2 + Q*x1^2, Q=8. Step is affine: x' = S(d,k) x,
//   S = [[1+nw, nw*qs],[nws, 1+nws*qs]],  nw = -2*ak, qs = Q*s, nws = nw*s,
//   s = d0*d1 in {-1,+1}.  ck cancels exactly.
// x_final = (prod_k S_k) x_init. 8 segments of n/8 iters; each thread builds
// a 2x2 segment product (6 FMAs/step); LDS combine folds 8 matrices into x.
// 16384 traj x 8 seg = 2048 waves = 8 waves/CU.
//
// R2 lesson: __launch_bounds__(256,2) capped VGPRs at 128 -> bufA/bufB
// (100 VGPRs) spilled to scratch (WRITE_SIZE 43 MB, dur unchanged). No cap:
// ~140-170 VGPRs still allows 2 waves/SIMD (threshold is 256), spill-free.

#define BLK  256
#define TPB  32          // trajectories per block
#define NSEG 8
#define UNR  25          // int2 loads per chunk per lane (125 = 5 chunks)

__global__ __launch_bounds__(BLK) void spsa_kernel(
    const float2* __restrict__ X0,
    const int2*   __restrict__ bits,   // (n, bs) int2 of {0,1} bits
    const float*  __restrict__ a_arr,
    float2*       __restrict__ out,
    int n, int bs, int A)
{
    __shared__ float s_nw[1024];             // n <= 1024 (n = 1000 here)
    __shared__ float s_m[NSEG][TPB][4];

    const int tid  = threadIdx.x;
    const int traj = tid & (TPB - 1);
    const int seg  = tid >> 5;
    int b          = blockIdx.x * TPB + traj;
    const bool act = (b < bs);
    if (!act) b = bs - 1;                    // clamp for safe (discarded) loads

    const int seglen = (n + NSEG - 1) / NSEG;        // 125 for n=1000
    const int k0  = seg * seglen;
    const int cnt = max(0, min(n, k0 + seglen) - k0);
    const int nch = cnt / UNR;                        // 5 for n=1000

    const int2* p = bits + (size_t)k0 * bs + b;

    int2 bufA[UNR], bufB[UNR];

    // Issue prologue loads FIRST so HBM latency hides under table setup.
    if (nch > 0) {
        #pragma unroll
        for (int j = 0; j < UNR; ++j) bufA[j] = p[(size_t)j * bs];
    }
    if (nch > 1) {
        const int2* q = p + (size_t)UNR * bs;
        #pragma unroll
        for (int j = 0; j < UNR; ++j) bufB[j] = q[(size_t)j * bs];
    }

    // Coefficient table: nw[k] = -2 * a[k] / (k+2+A)^0.602
    for (int k = tid; k < n; k += BLK) {
        float base = (float)(k + 2 + A);
        s_nw[k] = -2.0f * a_arr[k] / powf(base, 0.602f);
    }
    __syncthreads();

    // Segment product M = S_{k1-1} * ... * S_{k0}, accumulated in registers.
    float m00 = 1.f, m01 = 0.f, m10 = 0.f, m11 = 1.f;

    auto step = [&](int2 d, float nw) {
        unsigned sb = ((unsigned)(d.x ^ d.y)) << 31;        // sign of s
        float qs  = __uint_as_float(0x41000000u ^ sb);      // +-8.0
        float nws = __uint_as_float(__float_as_uint(nw) ^ sb);
        float u0 = fmaf(qs, m10, m00);
        float u1 = fmaf(qs, m11, m01);
        m00 = fmaf(nw,  u0, m00);
        m01 = fmaf(nw,  u1, m01);
        m10 = fmaf(nws, u0, m10);
        m11 = fmaf(nws, u1, m11);
    };

    // Software-pipelined, double-buffered (static reg indexing only).
    // Prologue loaded chunks 0 (A) and 1 (B); prefetch distance 2.
    for (int ch = 0; ch < nch; ch += 2) {
        {
            const int kb = k0 + ch * UNR;
            #pragma unroll
            for (int j = 0; j < UNR; ++j) step(bufA[j], s_nw[kb + j]);
        }
        if (ch + 2 < nch) {
            const int2* q = p + (size_t)(ch + 2) * UNR * bs;
            #pragma unroll
            for (int j = 0; j < UNR; ++j) bufA[j] = q[(size_t)j * bs];
        }
        if (ch + 1 < nch) {
            const int kb = k0 + (ch + 1) * UNR;
            #pragma unroll
            for (int j = 0; j < UNR; ++j) step(bufB[j], s_nw[kb + j]);
        }
        if (ch + 3 < nch) {
            const int2* q = p + (size_t)(ch + 3) * UNR * bs;
            #pragma unroll
            for (int j = 0; j < UNR; ++j) bufB[j] = q[(size_t)j * bs];
        }
    }
    for (int k = nch * UNR; k < cnt; ++k) step(p[(size_t)k * bs], s_nw[k0 + k]);

    s_m[seg][traj][0] = m00; s_m[seg][traj][1] = m01;
    s_m[seg][traj][2] = m10; s_m[seg][traj][3] = m11;
    __syncthreads();

    // Combine: first 32 threads fold the 8 segment matrices into x.
    if (seg == 0 && act) {
        float2 xin = X0[b];
        float v0 = xin.x * 20.0f - 10.0f;
        float v1 = xin.y * 20.0f - 10.0f;
        #pragma unroll
        for (int s = 0; s < NSEG; ++s) {
            float a00 = s_m[s][traj][0], a01 = s_m[s][traj][1];
            float a10 = s_m[s][traj][2], a11 = s_m[s][traj][3];
            float t0 = fmaf(a00, v0, a01 * v1);
            float t1 = fmaf(a10, v0, a11 * v1);
            v0 = t0; v1 = t1;
        }
        out[b] = make_float2(v0, v1);
    }
}

extern "C" void kernel_launch(void* const* d_in, const int* in_sizes, int n_in,
                              void* d_out, int out_size, void* d_ws, size_t ws_size,
                              hipStream_t stream) {
    const float2* X0   = (const float2*)d_in[0];
    const float*  a    = (const float*) d_in[1];
    // d_in[2] = c (cancels exactly, unused)
    const int2*   bits = (const int2*)  d_in[3];
    float2*       out  = (float2*)d_out;

    const int bs = in_sizes[0] / 2;
    const int n  = in_sizes[1];
    const int A  = (int)floor(0.1 * (double)n);

    const int grid = (bs + TPB - 1) / TPB;
    spsa_kernel<<<grid, BLK, 0, stream>>>(X0, bits, a, out, n, bs, A);
}